// Round 6
// baseline (309.421 us; speedup 1.0000x reference)
//
#include <hip/hip_runtime.h>
#include <math.h>

constexpr int B_    = 32;
constexpr int In_   = 2048;
constexpr int Din_  = 8;
constexpr int N_    = 64;
constexpr int Dout_ = 16;
constexpr int C_    = 32;
constexpr int ICP   = 64;     // In_/C_
constexpr int TILES = 4;      // 4 route tiles of 256 threads = 1024-thread block
constexpr float EPS = 1e-7f;

// Per-tile shared block (30.25 KB); 4 tiles + reduce buffers = 138 KB LDS.
struct TileSmem {
    float Us[N_][8];        // 2 KB
    float xs[ICP][8];       // 2 KB
    float lg[ICP][68];      // 17 KB (b128-aligned rows)
    float ps[4][ICP];       // 1 KB
    float inv_s[ICP];       // 256 B
    float ys[4][N_][8];     // 8 KB
};

// Squash over the 16 d's owned by a quad (thread holds 4 of them).
__device__ __forceinline__ float4 quad_squash(float a0, float a1, float a2, float a3)
{
    float sn = a0 * a0 + a1 * a1 + a2 * a2 + a3 * a3;
    sn += __shfl_xor(sn, 1);
    sn += __shfl_xor(sn, 2);          // full sum over 16 d (4 quad lanes)
    const float sc = sn / (1.f + sn) / sqrtf(sn + EPS);
    float4 r; r.x = a0 * sc; r.y = a1 * sc; r.z = a2 * sc; r.w = a3 * sc;
    return r;
}

// ---------------------------------------------------------------------------
// One routing tile for (b,c), executed by one 256-thread tile (tt = tile-
// local tid). vv = this thread's v[b][n4][4q4..+4) in registers. The s
// contribution accumulates into *acc (thread (n4,q4) owns s[n4][4q4..+4)).
// Identical math to the R0-validated route kernel.
// ---------------------------------------------------------------------------
__device__ __forceinline__ void route_tile(
    TileSmem* sm, int tt, int b, int c, float4 vv,
    const float* __restrict__ x, const float* __restrict__ W,
    float4* acc)
{
    const int w = tt >> 6, l = tt & 63;
    const int n4 = tt >> 2, q4 = tt & 3;

    // ---- U stage
    {
        const float vd[4] = {vv.x, vv.y, vv.z, vv.w};
        float pU[8] = {0, 0, 0, 0, 0, 0, 0, 0};
        #pragma unroll
        for (int dd = 0; dd < 4; ++dd) {
            const int d = q4 * 4 + dd;
            const float4* wp = (const float4*)(W + (((size_t)n4 * 32 + c) * 16 + d) * 8);
            const float4 w0 = wp[0], w1 = wp[1];
            const float v_ = vd[dd];
            pU[0] += v_ * w0.x; pU[1] += v_ * w0.y; pU[2] += v_ * w0.z; pU[3] += v_ * w0.w;
            pU[4] += v_ * w1.x; pU[5] += v_ * w1.y; pU[6] += v_ * w1.z; pU[7] += v_ * w1.w;
        }
        #pragma unroll
        for (int k = 0; k < 8; ++k) {
            pU[k] += __shfl_xor(pU[k], 1);
            pU[k] += __shfl_xor(pU[k], 2);
        }
        float2 u2; u2.x = pU[2 * q4]; u2.y = pU[2 * q4 + 1];
        *(float2*)&sm->Us[n4][2 * q4] = u2;
    }

    // ---- x fragment for lane's capsule i = l; wave 0 mirrors to LDS
    float xr[8];
    {
        const float4* xp = (const float4*)(x + ((size_t)b * In_ + c * ICP + l) * 8);
        const float4 x0 = xp[0], x1 = xp[1];
        xr[0] = x0.x; xr[1] = x0.y; xr[2] = x0.z; xr[3] = x0.w;
        xr[4] = x1.x; xr[5] = x1.y; xr[6] = x1.z; xr[7] = x1.w;
        if (w == 0) { *(float4*)&sm->xs[l][0] = x0; *(float4*)&sm->xs[l][4] = x1; }
    }
    __syncthreads();

    // ---- logits+exp: wave w covers n in [16w,16w+16); lane = i
    {
        float e[16];
        float ssum = 0.f;
        #pragma unroll
        for (int nn = 0; nn < 16; ++nn) {
            const int n = w * 16 + nn;
            const float4 u0 = *(const float4*)&sm->Us[n][0];
            const float4 u1 = *(const float4*)&sm->Us[n][4];
            const float a = u0.x * xr[0] + u0.y * xr[1] + u0.z * xr[2] + u0.w * xr[3]
                          + u1.x * xr[4] + u1.y * xr[5] + u1.z * xr[6] + u1.w * xr[7];
            const float ee = __expf(a);    // logits bounded (validated earlier)
            e[nn] = ee; ssum += ee;
        }
        #pragma unroll
        for (int qq = 0; qq < 4; ++qq) {
            float4 o;
            o.x = e[qq * 4 + 0]; o.y = e[qq * 4 + 1]; o.z = e[qq * 4 + 2]; o.w = e[qq * 4 + 3];
            *(float4*)&sm->lg[l][w * 16 + qq * 4] = o;
        }
        sm->ps[w][l] = ssum;
    }
    __syncthreads();

    if (tt < 64) sm->inv_s[tt] = 1.f / (sm->ps[0][tt] + sm->ps[1][tt] + sm->ps[2][tt] + sm->ps[3][tt]);
    __syncthreads();

    // ---- y stage: wave w covers i in [16w,16w+16)
    {
        const int nq = l >> 2, kq = l & 3;
        float y[8] = {0, 0, 0, 0, 0, 0, 0, 0};
        #pragma unroll
        for (int ii = 0; ii < 16; ++ii) {
            const int i = w * 16 + ii;
            const float4 cw = *(const float4*)&sm->lg[i][nq * 4];
            const float iv = sm->inv_s[i];
            const float2 x2 = *(const float2*)&sm->xs[i][kq * 2];
            const float c0 = cw.x * iv, c1 = cw.y * iv, c2 = cw.z * iv, c3 = cw.w * iv;
            y[0] += c0 * x2.x; y[1] += c0 * x2.y;
            y[2] += c1 * x2.x; y[3] += c1 * x2.y;
            y[4] += c2 * x2.x; y[5] += c2 * x2.y;
            y[6] += c3 * x2.x; y[7] += c3 * x2.y;
        }
        #pragma unroll
        for (int jj = 0; jj < 4; ++jj) {
            float2 o; o.x = y[2 * jj]; o.y = y[2 * jj + 1];
            *(float2*)&sm->ys[w][nq * 4 + jj][kq * 2] = o;
        }
    }
    __syncthreads();

    // ---- s stage: accumulate this c's contribution
    {
        float yn[8];
        #pragma unroll
        for (int k = 0; k < 8; ++k)
            yn[k] = sm->ys[0][n4][k] + sm->ys[1][n4][k] + sm->ys[2][n4][k] + sm->ys[3][n4][k];
        float o[4];
        #pragma unroll
        for (int dd = 0; dd < 4; ++dd) {
            const int d = q4 * 4 + dd;
            const float4* wp = (const float4*)(W + (((size_t)n4 * 32 + c) * 16 + d) * 8);
            const float4 w0 = wp[0], w1 = wp[1];
            o[dd] = w0.x * yn[0] + w0.y * yn[1] + w0.z * yn[2] + w0.w * yn[3]
                  + w1.x * yn[4] + w1.y * yn[5] + w1.z * yn[6] + w1.w * yn[7];
        }
        acc->x += o[0]; acc->y += o[1]; acc->z += o[2]; acc->w += o[3];
    }
    __syncthreads();   // LDS dead before next round reuses it
}

// ---------------------------------------------------------------------------
// One block per batch b; 1024 threads = 4 tiles x 256. Tile handles c in
// [8*tile, 8*tile+8). ZERO cross-block sync (R4/R5 measured ~150ns per
// block-fence-event at device scope — the only winning count is zero).
// All reductions via LDS + __syncthreads.
// ---------------------------------------------------------------------------
__global__ __launch_bounds__(1024, 1) void caps_one(
    const float* __restrict__ x, const float* __restrict__ W,
    const float* __restrict__ bias, float* __restrict__ out)
{
    __shared__ TileSmem sm[TILES];       // 121 KB
    __shared__ float vpart[TILES][N_][16]; // 16 KB (v0 partials, then s partials)
    __shared__ float xbars[C_][8];       // 1 KB

    const int b = blockIdx.x;
    const int t = threadIdx.x;
    const int tile = t >> 8, tt = t & 255;
    const int n4 = tt >> 2, q4 = tt & 3;
    TileSmem* tsm = &sm[tile];

    // ---- xbar[c][k] = mean_i x[b, c*64+i, k]  (threads 0..255)
    if (t < 256) {
        const int c = t >> 3, k = t & 7;
        const float* xp = x + (size_t)b * In_ * Din_ + (size_t)c * ICP * Din_ + k;
        float acc = 0.f;
        #pragma unroll 8
        for (int i = 0; i < ICP; ++i) acc += xp[i * Din_];
        xbars[c][k] = acc * (1.f / 64.f);
    }
    __syncthreads();

    // ---- v0 partial over this tile's 8 c's: thread (n4,q4) covers 4 d's
    {
        float a[4] = {0.f, 0.f, 0.f, 0.f};
        #pragma unroll
        for (int cc = 0; cc < 8; ++cc) {
            const int c = tile * 8 + cc;
            const float xb0 = xbars[c][0], xb1 = xbars[c][1], xb2 = xbars[c][2], xb3 = xbars[c][3];
            const float xb4 = xbars[c][4], xb5 = xbars[c][5], xb6 = xbars[c][6], xb7 = xbars[c][7];
            #pragma unroll
            for (int dd = 0; dd < 4; ++dd) {
                const int d = q4 * 4 + dd;
                const float4* wp = (const float4*)(W + (((size_t)n4 * 32 + c) * 16 + d) * 8);
                const float4 w0 = wp[0], w1 = wp[1];
                a[dd] += w0.x * xb0 + w0.y * xb1 + w0.z * xb2 + w0.w * xb3
                       + w1.x * xb4 + w1.y * xb5 + w1.z * xb6 + w1.w * xb7;
            }
        }
        float4 o; o.x = a[0]; o.y = a[1]; o.z = a[2]; o.w = a[3];
        *(float4*)&vpart[tile][n4][q4 * 4] = o;
    }
    __syncthreads();

    // ---- v0 = squash(sum_tiles + bias): every thread computes its (n4,q4) slice
    float4 vv0;
    {
        const float4 p0 = *(const float4*)&vpart[0][n4][q4 * 4];
        const float4 p1 = *(const float4*)&vpart[1][n4][q4 * 4];
        const float4 p2 = *(const float4*)&vpart[2][n4][q4 * 4];
        const float4 p3 = *(const float4*)&vpart[3][n4][q4 * 4];
        const float4 bi = *(const float4*)(bias + n4 * 16 + q4 * 4);
        vv0 = quad_squash(p0.x + p1.x + p2.x + p3.x + bi.x,
                          p0.y + p1.y + p2.y + p3.y + bi.y,
                          p0.z + p1.z + p2.z + p3.z + bi.z,
                          p0.w + p1.w + p2.w + p3.w + bi.w);
    }
    __syncthreads();   // vpart reads done before s-partial reuse

    // ---- routing iteration 1: 8 rounds, tile handles c = tile*8 + r
    {
        float4 acc = {0.f, 0.f, 0.f, 0.f};
        #pragma unroll 2
        for (int r = 0; r < 8; ++r)
            route_tile(tsm, tt, b, tile * 8 + r, vv0, x, W, &acc);
        *(float4*)&vpart[tile][n4][q4 * 4] = acc;
    }
    __syncthreads();

    // ---- vsum = v0 + squash(sum s1 + bias)
    float4 vv1;
    {
        const float4 p0 = *(const float4*)&vpart[0][n4][q4 * 4];
        const float4 p1 = *(const float4*)&vpart[1][n4][q4 * 4];
        const float4 p2 = *(const float4*)&vpart[2][n4][q4 * 4];
        const float4 p3 = *(const float4*)&vpart[3][n4][q4 * 4];
        const float4 bi = *(const float4*)(bias + n4 * 16 + q4 * 4);
        const float4 sq = quad_squash(p0.x + p1.x + p2.x + p3.x + bi.x,
                                      p0.y + p1.y + p2.y + p3.y + bi.y,
                                      p0.z + p1.z + p2.z + p3.z + bi.z,
                                      p0.w + p1.w + p2.w + p3.w + bi.w);
        vv1.x = vv0.x + sq.x; vv1.y = vv0.y + sq.y;
        vv1.z = vv0.z + sq.z; vv1.w = vv0.w + sq.w;
    }
    __syncthreads();   // vpart reads done before iter-2 reuse

    // ---- routing iteration 2
    {
        float4 acc = {0.f, 0.f, 0.f, 0.f};
        #pragma unroll 2
        for (int r = 0; r < 8; ++r)
            route_tile(tsm, tt, b, tile * 8 + r, vv1, x, W, &acc);
        *(float4*)&vpart[tile][n4][q4 * 4] = acc;
    }
    __syncthreads();

    // ---- final: out[b] = squash(sum s2 + bias), written by tile 0
    if (tile == 0) {
        const float4 p0 = *(const float4*)&vpart[0][n4][q4 * 4];
        const float4 p1 = *(const float4*)&vpart[1][n4][q4 * 4];
        const float4 p2 = *(const float4*)&vpart[2][n4][q4 * 4];
        const float4 p3 = *(const float4*)&vpart[3][n4][q4 * 4];
        const float4 bi = *(const float4*)(bias + n4 * 16 + q4 * 4);
        const float4 r = quad_squash(p0.x + p1.x + p2.x + p3.x + bi.x,
                                     p0.y + p1.y + p2.y + p3.y + bi.y,
                                     p0.z + p1.z + p2.z + p3.z + bi.z,
                                     p0.w + p1.w + p2.w + p3.w + bi.w);
        *(float4*)(out + (size_t)b * 1024 + n4 * 16 + q4 * 4) = r;
    }
}

extern "C" void kernel_launch(void* const* d_in, const int* in_sizes, int n_in,
                              void* d_out, int out_size, void* d_ws, size_t ws_size,
                              hipStream_t stream) {
    const float* x    = (const float*)d_in[0];   // [B, In, Din]
    const float* W    = (const float*)d_in[1];   // [N, C, Dout, Din]
    const float* bias = (const float*)d_in[2];   // [N, Dout]
    float* out = (float*)d_out;                  // [B, N, Dout]

    // Single plain dispatch; no workspace, no memset, no cross-block sync.
    caps_one<<<B_, TILES * 256, 0, stream>>>(x, W, bias, out);
}

// Round 7
// 96.887 us; speedup vs baseline: 3.1936x; 3.1936x over previous
//
#include <hip/hip_runtime.h>
#include <math.h>

constexpr int B_    = 32;
constexpr int In_   = 2048;
constexpr int Din_  = 8;
constexpr int N_    = 64;
constexpr int Dout_ = 16;
constexpr int C_    = 32;
constexpr int ICP   = 64;     // In_/C_
constexpr float EPS = 1e-7f;

// ---------------------------------------------------------------------------
// K1: v0 = squash(sum_c W[n,c,:,:].xbar[c,:] + bias). 8 blocks per b
// (R0-validated).
// ---------------------------------------------------------------------------
__global__ __launch_bounds__(256) void caps_v0(
    const float* __restrict__ x, const float* __restrict__ W,
    const float* __restrict__ bias, float* __restrict__ v0)
{
    const int b = blockIdx.x >> 3, j = blockIdx.x & 7;
    const int t = threadIdx.x;

    __shared__ float xbar[C_][Din_];

    {
        const int c = t >> 3, k = t & 7;
        const float* xp = x + (size_t)b * In_ * Din_ + (size_t)c * ICP * Din_ + k;
        float acc = 0.f;
        #pragma unroll 8
        for (int i = 0; i < ICP; ++i) acc += xp[i * Din_];
        xbar[c][k] = acc * (1.f / 64.f);
    }
    __syncthreads();

    {
        const int nl = t >> 5, lane32 = t & 31;
        const int d = lane32 >> 1, h = lane32 & 1;
        const int n = j * 8 + nl;

        float a = 0.f;
        #pragma unroll
        for (int cc = 0; cc < 16; ++cc) {
            const int c2 = cc * 2 + h;
            const float4* wp = (const float4*)(W + (((size_t)n * C_ + c2) * Dout_ + d) * Din_);
            const float4 w0 = wp[0], w1 = wp[1];
            a += w0.x * xbar[c2][0] + w0.y * xbar[c2][1] + w0.z * xbar[c2][2] + w0.w * xbar[c2][3]
               + w1.x * xbar[c2][4] + w1.y * xbar[c2][5] + w1.z * xbar[c2][6] + w1.w * xbar[c2][7];
        }
        a += __shfl_xor(a, 1);
        a += bias[n * Dout_ + d];

        float sn = a * a;
        sn += __shfl_xor(sn, 2);
        sn += __shfl_xor(sn, 4);
        sn += __shfl_xor(sn, 8);
        sn += __shfl_xor(sn, 16);
        const float sc = sn / (1.f + sn) / sqrtf(sn + EPS);
        if (h == 0) v0[(size_t)b * 1024 + n * Dout_ + d] = a * sc;
    }
}

// ---------------------------------------------------------------------------
// Routing body for one (b,c): 256 threads. vv = thread (n4,q4)'s slice of the
// accumulated v. Writes s_out[b][c][n][d]. (R0/R4-validated.)
// ---------------------------------------------------------------------------
struct RouteSmem {
    float Us[N_][8];        // 2 KB
    float xs[ICP][8];       // 2 KB
    float lg[ICP][68];      // 17 KB
    float ps[4][ICP];       // 1 KB
    float inv_s[ICP];       // 256 B
    float ys[4][N_][8];     // 8 KB
};

__device__ __forceinline__ void route_body(
    RouteSmem* sm, int b, int c, float4 vv,
    const float* __restrict__ x, const float* __restrict__ W,
    float* __restrict__ s_out)
{
    const int t = threadIdx.x;
    const int w = t >> 6, l = t & 63;
    const int n4 = t >> 2, q4 = t & 3;

    // ---- U stage
    {
        const float vd[4] = {vv.x, vv.y, vv.z, vv.w};
        float pU[8] = {0, 0, 0, 0, 0, 0, 0, 0};
        #pragma unroll
        for (int dd = 0; dd < 4; ++dd) {
            const int d = q4 * 4 + dd;
            const float4* wp = (const float4*)(W + (((size_t)n4 * 32 + c) * 16 + d) * 8);
            const float4 w0 = wp[0], w1 = wp[1];
            const float v_ = vd[dd];
            pU[0] += v_ * w0.x; pU[1] += v_ * w0.y; pU[2] += v_ * w0.z; pU[3] += v_ * w0.w;
            pU[4] += v_ * w1.x; pU[5] += v_ * w1.y; pU[6] += v_ * w1.z; pU[7] += v_ * w1.w;
        }
        #pragma unroll
        for (int k = 0; k < 8; ++k) {
            pU[k] += __shfl_xor(pU[k], 1);
            pU[k] += __shfl_xor(pU[k], 2);
        }
        float2 u2; u2.x = pU[2 * q4]; u2.y = pU[2 * q4 + 1];
        *(float2*)&sm->Us[n4][2 * q4] = u2;
    }

    // ---- x fragment; wave 0 mirrors to LDS
    float xr[8];
    {
        const float4* xp = (const float4*)(x + ((size_t)b * In_ + c * ICP + l) * 8);
        const float4 x0 = xp[0], x1 = xp[1];
        xr[0] = x0.x; xr[1] = x0.y; xr[2] = x0.z; xr[3] = x0.w;
        xr[4] = x1.x; xr[5] = x1.y; xr[6] = x1.z; xr[7] = x1.w;
        if (w == 0) { *(float4*)&sm->xs[l][0] = x0; *(float4*)&sm->xs[l][4] = x1; }
    }
    __syncthreads();

    // ---- logits+exp
    {
        float e[16];
        float ssum = 0.f;
        #pragma unroll
        for (int nn = 0; nn < 16; ++nn) {
            const int n = w * 16 + nn;
            const float4 u0 = *(const float4*)&sm->Us[n][0];
            const float4 u1 = *(const float4*)&sm->Us[n][4];
            const float a = u0.x * xr[0] + u0.y * xr[1] + u0.z * xr[2] + u0.w * xr[3]
                          + u1.x * xr[4] + u1.y * xr[5] + u1.z * xr[6] + u1.w * xr[7];
            const float ee = __expf(a);    // logits bounded (validated R0/R4)
            e[nn] = ee; ssum += ee;
        }
        #pragma unroll
        for (int qq = 0; qq < 4; ++qq) {
            float4 o;
            o.x = e[qq * 4 + 0]; o.y = e[qq * 4 + 1]; o.z = e[qq * 4 + 2]; o.w = e[qq * 4 + 3];
            *(float4*)&sm->lg[l][w * 16 + qq * 4] = o;
        }
        sm->ps[w][l] = ssum;
    }
    __syncthreads();

    if (t < 64) sm->inv_s[t] = 1.f / (sm->ps[0][t] + sm->ps[1][t] + sm->ps[2][t] + sm->ps[3][t]);
    __syncthreads();

    // ---- y stage
    {
        const int nq = l >> 2, kq = l & 3;
        float y[8] = {0, 0, 0, 0, 0, 0, 0, 0};
        #pragma unroll
        for (int ii = 0; ii < 16; ++ii) {
            const int i = w * 16 + ii;
            const float4 cw = *(const float4*)&sm->lg[i][nq * 4];
            const float iv = sm->inv_s[i];
            const float2 x2 = *(const float2*)&sm->xs[i][kq * 2];
            const float c0 = cw.x * iv, c1 = cw.y * iv, c2 = cw.z * iv, c3 = cw.w * iv;
            y[0] += c0 * x2.x; y[1] += c0 * x2.y;
            y[2] += c1 * x2.x; y[3] += c1 * x2.y;
            y[4] += c2 * x2.x; y[5] += c2 * x2.y;
            y[6] += c3 * x2.x; y[7] += c3 * x2.y;
        }
        #pragma unroll
        for (int jj = 0; jj < 4; ++jj) {
            float2 o; o.x = y[2 * jj]; o.y = y[2 * jj + 1];
            *(float2*)&sm->ys[w][nq * 4 + jj][kq * 2] = o;
        }
    }
    __syncthreads();

    // ---- s stage
    {
        float yn[8];
        #pragma unroll
        for (int k = 0; k < 8; ++k)
            yn[k] = sm->ys[0][n4][k] + sm->ys[1][n4][k] + sm->ys[2][n4][k] + sm->ys[3][n4][k];
        float4 o;
        float* op = (float*)&o;
        #pragma unroll
        for (int dd = 0; dd < 4; ++dd) {
            const int d = q4 * 4 + dd;
            const float4* wp = (const float4*)(W + (((size_t)n4 * 32 + c) * 16 + d) * 8);
            const float4 w0 = wp[0], w1 = wp[1];
            op[dd] = w0.x * yn[0] + w0.y * yn[1] + w0.z * yn[2] + w0.w * yn[3]
                   + w1.x * yn[4] + w1.y * yn[5] + w1.z * yn[6] + w1.w * yn[7];
        }
        *(float4*)(s_out + (((size_t)b * 32 + c) * 64 + n4) * 16 + q4 * 4) = o;
    }
}

// K2: route1 (v_src = v0). 1024 blocks = (b,c).
__global__ __launch_bounds__(256) void caps_route(
    const float* __restrict__ x, const float* __restrict__ W,
    const float* __restrict__ v_src, float* __restrict__ s_out)
{
    __shared__ RouteSmem sm;
    const int b = blockIdx.x >> 5, c = blockIdx.x & 31;
    const int n4 = threadIdx.x >> 2, q4 = threadIdx.x & 3;
    const float4 vv = *(const float4*)(v_src + ((size_t)b * 64 + n4) * 16 + q4 * 4);
    route_body(&sm, b, c, vv, x, W, s_out);
}

// ---------------------------------------------------------------------------
// K3: fused vsum + route2. Each block redundantly reduces the 32 c-slices of
// s1 in registers (R4-validated vsum_tile), forms vsum = v0 + squash(.), then
// runs route2 for its (b,c). Eliminates the reduce1 dispatch.
// ---------------------------------------------------------------------------
__global__ __launch_bounds__(256) void caps_vroute(
    const float* __restrict__ x, const float* __restrict__ W,
    const float* __restrict__ bias, const float* __restrict__ v0buf,
    const float* __restrict__ s1, float* __restrict__ s2)
{
    __shared__ RouteSmem sm;
    const int b = blockIdx.x >> 5, c = blockIdx.x & 31;
    const int t = threadIdx.x, n4 = t >> 2, q4 = t & 3;

    // vsum_tile: sum s1 over c + bias, squash, add v0 (in registers)
    float a0 = 0.f, a1 = 0.f, a2 = 0.f, a3 = 0.f;
    const float* sp = s1 + ((size_t)b * 32 * 64 + n4) * 16 + q4 * 4;
    #pragma unroll 8
    for (int cc = 0; cc < 32; ++cc) {
        const float4 sv = *(const float4*)(sp + (size_t)cc * 1024);
        a0 += sv.x; a1 += sv.y; a2 += sv.z; a3 += sv.w;
    }
    const float4 bi = *(const float4*)(bias + n4 * 16 + q4 * 4);
    a0 += bi.x; a1 += bi.y; a2 += bi.z; a3 += bi.w;

    float sn = a0 * a0 + a1 * a1 + a2 * a2 + a3 * a3;
    sn += __shfl_xor(sn, 1);
    sn += __shfl_xor(sn, 2);          // full sum over the 16 d (quad lanes)
    const float sc = sn / (1.f + sn) / sqrtf(sn + EPS);

    const float4 v0v = *(const float4*)(v0buf + (size_t)b * 1024 + n4 * 16 + q4 * 4);
    float4 vv;
    vv.x = v0v.x + a0 * sc; vv.y = v0v.y + a1 * sc;
    vv.z = v0v.z + a2 * sc; vv.w = v0v.w + a3 * sc;

    route_body(&sm, b, c, vv, x, W, s2);
}

// ---------------------------------------------------------------------------
// K4: final reduce s2 over c + bias + squash -> out. (R0-validated.)
// ---------------------------------------------------------------------------
__global__ __launch_bounds__(256) void caps_reduce(
    const float* __restrict__ s_src, const float* __restrict__ bias,
    float* __restrict__ dst)
{
    const int b = blockIdx.x >> 3, j = blockIdx.x & 7;
    const int t = threadIdx.x;
    const int nl = t >> 5, lane32 = t & 31;
    const int d = lane32 >> 1, h = lane32 & 1;
    const int n = j * 8 + nl;

    float a = 0.f;
    #pragma unroll
    for (int cc = 0; cc < 16; ++cc) {
        const int c2 = cc * 2 + h;
        a += s_src[(((size_t)b * 32 + c2) * 64 + n) * 16 + d];
    }
    a += __shfl_xor(a, 1);
    a += bias[n * Dout_ + d];

    float sn = a * a;
    sn += __shfl_xor(sn, 2);
    sn += __shfl_xor(sn, 4);
    sn += __shfl_xor(sn, 8);
    sn += __shfl_xor(sn, 16);
    const float sc = sn / (1.f + sn) / sqrtf(sn + EPS);
    if (h == 0) dst[(size_t)b * 1024 + n * Dout_ + d] = a * sc;
}

extern "C" void kernel_launch(void* const* d_in, const int* in_sizes, int n_in,
                              void* d_out, int out_size, void* d_ws, size_t ws_size,
                              hipStream_t stream) {
    const float* x    = (const float*)d_in[0];   // [B, In, Din]
    const float* W    = (const float*)d_in[1];   // [N, C, Dout, Din]
    const float* bias = (const float*)d_in[2];   // [N, Dout]
    float* out = (float*)d_out;                  // [B, N, Dout]

    float* ws  = (float*)d_ws;
    float* s1  = ws;                                   // B*C*N*Dout = 1,048,576 f
    float* s2  = s1 + (size_t)B_ * C_ * N_ * Dout_;    // 1,048,576 f
    float* v0  = s2 + (size_t)B_ * C_ * N_ * Dout_;    // B*N*Dout = 32,768 f

    caps_v0    <<<256,  256, 0, stream>>>(x, W, bias, v0);
    caps_route <<<1024, 256, 0, stream>>>(x, W, v0, s1);
    caps_vroute<<<1024, 256, 0, stream>>>(x, W, bias, v0, s1, s2);
    caps_reduce<<<256,  256, 0, stream>>>(s2, bias, out);
}

// Round 8
// 91.966 us; speedup vs baseline: 3.3645x; 1.0535x over previous
//
#include <hip/hip_runtime.h>
#include <hip/hip_fp16.h>
#include <math.h>

constexpr int B_    = 32;
constexpr int In_   = 2048;
constexpr int Din_  = 8;
constexpr int N_    = 64;
constexpr int Dout_ = 16;
constexpr int C_    = 32;
constexpr int ICP   = 64;     // In_/C_
constexpr float EPS = 1e-7f;

// ---------------------------------------------------------------------------
// K1: v0 = squash(sum_c W[n,c,:,:].xbar[c,:] + bias). 8 blocks per b
// (R0-validated, unchanged).
// ---------------------------------------------------------------------------
__global__ __launch_bounds__(256) void caps_v0(
    const float* __restrict__ x, const float* __restrict__ W,
    const float* __restrict__ bias, float* __restrict__ v0)
{
    const int b = blockIdx.x >> 3, j = blockIdx.x & 7;
    const int t = threadIdx.x;

    __shared__ float xbar[C_][Din_];

    {
        const int c = t >> 3, k = t & 7;
        const float* xp = x + (size_t)b * In_ * Din_ + (size_t)c * ICP * Din_ + k;
        float acc = 0.f;
        #pragma unroll 8
        for (int i = 0; i < ICP; ++i) acc += xp[i * Din_];
        xbar[c][k] = acc * (1.f / 64.f);
    }
    __syncthreads();

    {
        const int nl = t >> 5, lane32 = t & 31;
        const int d = lane32 >> 1, h = lane32 & 1;
        const int n = j * 8 + nl;

        float a = 0.f;
        #pragma unroll
        for (int cc = 0; cc < 16; ++cc) {
            const int c2 = cc * 2 + h;
            const float4* wp = (const float4*)(W + (((size_t)n * C_ + c2) * Dout_ + d) * Din_);
            const float4 w0 = wp[0], w1 = wp[1];
            a += w0.x * xbar[c2][0] + w0.y * xbar[c2][1] + w0.z * xbar[c2][2] + w0.w * xbar[c2][3]
               + w1.x * xbar[c2][4] + w1.y * xbar[c2][5] + w1.z * xbar[c2][6] + w1.w * xbar[c2][7];
        }
        a += __shfl_xor(a, 1);
        a += bias[n * Dout_ + d];

        float sn = a * a;
        sn += __shfl_xor(sn, 2);
        sn += __shfl_xor(sn, 4);
        sn += __shfl_xor(sn, 8);
        sn += __shfl_xor(sn, 16);
        const float sc = sn / (1.f + sn) / sqrtf(sn + EPS);
        if (h == 0) v0[(size_t)b * 1024 + n * Dout_ + d] = a * sc;
    }
}

// ---------------------------------------------------------------------------
// K2/K4: routing iteration, occupancy-optimized.
//  - lg stored as f16 (e' = exp(min(a,12)-5); shift cancels in softmax,
//    clamp+shift keep e' in f16 range even for iter2's |v|<2 logits).
//  - LDS 30.25 KB -> 21.75 KB => 7 blocks/CU (28 waves vs 20).
//  - e stored as computed (no e[16] array) => lower VGPR; launch_bounds(256,7).
// ---------------------------------------------------------------------------
struct RouteSmem {
    float  Us[N_][8];       // 2 KB
    float  xs[ICP][8];      // 2 KB
    ushort lg[ICP][68];     // 8.5 KB (f16 e-values; 34-dword row stride -> 2-way free)
    float  ps[4][ICP];      // 1 KB
    float  inv_s[ICP];      // 256 B
    float  ys[4][N_][8];    // 8 KB
};                          // total 21.75 KB

__device__ __forceinline__ void route_body(
    RouteSmem* sm, int b, int c, float4 vv,
    const float* __restrict__ x, const float* __restrict__ W,
    float* __restrict__ s_out)
{
    const int t = threadIdx.x;
    const int w = t >> 6, l = t & 63;
    const int n4 = t >> 2, q4 = t & 3;

    // ---- U stage
    {
        const float vd[4] = {vv.x, vv.y, vv.z, vv.w};
        float pU[8] = {0, 0, 0, 0, 0, 0, 0, 0};
        #pragma unroll
        for (int dd = 0; dd < 4; ++dd) {
            const int d = q4 * 4 + dd;
            const float4* wp = (const float4*)(W + (((size_t)n4 * 32 + c) * 16 + d) * 8);
            const float4 w0 = wp[0], w1 = wp[1];
            const float v_ = vd[dd];
            pU[0] += v_ * w0.x; pU[1] += v_ * w0.y; pU[2] += v_ * w0.z; pU[3] += v_ * w0.w;
            pU[4] += v_ * w1.x; pU[5] += v_ * w1.y; pU[6] += v_ * w1.z; pU[7] += v_ * w1.w;
        }
        #pragma unroll
        for (int k = 0; k < 8; ++k) {
            pU[k] += __shfl_xor(pU[k], 1);
            pU[k] += __shfl_xor(pU[k], 2);
        }
        float2 u2; u2.x = pU[2 * q4]; u2.y = pU[2 * q4 + 1];
        *(float2*)&sm->Us[n4][2 * q4] = u2;
    }

    // ---- x fragment; wave 0 mirrors to LDS
    float xr[8];
    {
        const float4* xp = (const float4*)(x + ((size_t)b * In_ + c * ICP + l) * 8);
        const float4 x0 = xp[0], x1 = xp[1];
        xr[0] = x0.x; xr[1] = x0.y; xr[2] = x0.z; xr[3] = x0.w;
        xr[4] = x1.x; xr[5] = x1.y; xr[6] = x1.z; xr[7] = x1.w;
        if (w == 0) { *(float4*)&sm->xs[l][0] = x0; *(float4*)&sm->xs[l][4] = x1; }
    }
    __syncthreads();

    // ---- logits+exp: wave w covers n in [16w,16w+16); lane = i.
    // e' = exp(min(a,12)-5) stored f16 pairwise as computed.
    {
        float ssum = 0.f;
        float eprev = 0.f;
        #pragma unroll
        for (int nn = 0; nn < 16; ++nn) {
            const int n = w * 16 + nn;
            const float4 u0 = *(const float4*)&sm->Us[n][0];
            const float4 u1 = *(const float4*)&sm->Us[n][4];
            const float a = u0.x * xr[0] + u0.y * xr[1] + u0.z * xr[2] + u0.w * xr[3]
                          + u1.x * xr[4] + u1.y * xr[5] + u1.z * xr[6] + u1.w * xr[7];
            const float ee = __expf(fminf(a, 12.f) - 5.f);
            ssum += ee;
            if (nn & 1) {
                const __half2 h2 = __floats2half2_rn(eprev, ee);
                *(__half2*)&sm->lg[l][w * 16 + (nn - 1)] = h2;
            } else {
                eprev = ee;
            }
        }
        sm->ps[w][l] = ssum;
    }
    __syncthreads();

    if (t < 64) sm->inv_s[t] = 1.f / (sm->ps[0][t] + sm->ps[1][t] + sm->ps[2][t] + sm->ps[3][t]);
    __syncthreads();

    // ---- y stage: wave w covers i in [16w,16w+16); lane = (nq=l>>2, kq=l&3)
    {
        const int nq = l >> 2, kq = l & 3;
        float y[8] = {0, 0, 0, 0, 0, 0, 0, 0};
        #pragma unroll
        for (int ii = 0; ii < 16; ++ii) {
            const int i = w * 16 + ii;
            // 4 f16 e-values at lg[i][nq*4] (8B aligned: 136*i + 8*nq)
            const uint2 cw2 = *(const uint2*)&sm->lg[i][nq * 4];
            const float2 f01 = __half22float2(*(const __half2*)&cw2.x);
            const float2 f23 = __half22float2(*(const __half2*)&cw2.y);
            const float iv = sm->inv_s[i];
            const float2 x2 = *(const float2*)&sm->xs[i][kq * 2];
            const float c0 = f01.x * iv, c1 = f01.y * iv, c2 = f23.x * iv, c3 = f23.y * iv;
            y[0] += c0 * x2.x; y[1] += c0 * x2.y;
            y[2] += c1 * x2.x; y[3] += c1 * x2.y;
            y[4] += c2 * x2.x; y[5] += c2 * x2.y;
            y[6] += c3 * x2.x; y[7] += c3 * x2.y;
        }
        #pragma unroll
        for (int jj = 0; jj < 4; ++jj) {
            float2 o; o.x = y[2 * jj]; o.y = y[2 * jj + 1];
            *(float2*)&sm->ys[w][nq * 4 + jj][kq * 2] = o;
        }
    }
    __syncthreads();

    // ---- s stage
    {
        float yn[8];
        #pragma unroll
        for (int k = 0; k < 8; ++k)
            yn[k] = sm->ys[0][n4][k] + sm->ys[1][n4][k] + sm->ys[2][n4][k] + sm->ys[3][n4][k];
        float4 o;
        float* op = (float*)&o;
        #pragma unroll
        for (int dd = 0; dd < 4; ++dd) {
            const int d = q4 * 4 + dd;
            const float4* wp = (const float4*)(W + (((size_t)n4 * 32 + c) * 16 + d) * 8);
            const float4 w0 = wp[0], w1 = wp[1];
            op[dd] = w0.x * yn[0] + w0.y * yn[1] + w0.z * yn[2] + w0.w * yn[3]
                   + w1.x * yn[4] + w1.y * yn[5] + w1.z * yn[6] + w1.w * yn[7];
        }
        *(float4*)(s_out + (((size_t)b * 32 + c) * 64 + n4) * 16 + q4 * 4) = o;
    }
}

__global__ __launch_bounds__(256, 7) void caps_route(
    const float* __restrict__ x, const float* __restrict__ W,
    const float* __restrict__ v_src, float* __restrict__ s_out)
{
    __shared__ RouteSmem sm;
    const int b = blockIdx.x >> 5, c = blockIdx.x & 31;
    const int n4 = threadIdx.x >> 2, q4 = threadIdx.x & 3;
    const float4 vv = *(const float4*)(v_src + ((size_t)b * 64 + n4) * 16 + q4 * 4);
    route_body(&sm, b, c, vv, x, W, s_out);
}

// ---------------------------------------------------------------------------
// K3/K5: reduce s over c + bias + squash -> dst; optionally dst += vadd.
// (R0-validated, unchanged.)
// ---------------------------------------------------------------------------
__global__ __launch_bounds__(256) void caps_reduce(
    const float* __restrict__ s_src, const float* __restrict__ bias,
    const float* __restrict__ vadd, float* __restrict__ dst)
{
    const int b = blockIdx.x >> 3, j = blockIdx.x & 7;
    const int t = threadIdx.x;
    const int nl = t >> 5, lane32 = t & 31;
    const int d = lane32 >> 1, h = lane32 & 1;
    const int n = j * 8 + nl;

    float a = 0.f;
    #pragma unroll
    for (int cc = 0; cc < 16; ++cc) {
        const int c2 = cc * 2 + h;
        a += s_src[(((size_t)b * 32 + c2) * 64 + n) * 16 + d];
    }
    a += __shfl_xor(a, 1);
    a += bias[n * Dout_ + d];

    float sn = a * a;
    sn += __shfl_xor(sn, 2);
    sn += __shfl_xor(sn, 4);
    sn += __shfl_xor(sn, 8);
    sn += __shfl_xor(sn, 16);
    const float sc = sn / (1.f + sn) / sqrtf(sn + EPS);
    float val = a * sc;
    if (vadd) val += vadd[(size_t)b * 1024 + n * Dout_ + d];
    if (h == 0) dst[(size_t)b * 1024 + n * Dout_ + d] = val;
}

extern "C" void kernel_launch(void* const* d_in, const int* in_sizes, int n_in,
                              void* d_out, int out_size, void* d_ws, size_t ws_size,
                              hipStream_t stream) {
    const float* x    = (const float*)d_in[0];   // [B, In, Din]
    const float* W    = (const float*)d_in[1];   // [N, C, Dout, Din]
    const float* bias = (const float*)d_in[2];   // [N, Dout]
    float* out = (float*)d_out;                  // [B, N, Dout]

    float* ws   = (float*)d_ws;
    float* s1   = ws;                                   // 1,048,576 f
    float* s2   = s1   + (size_t)B_ * C_ * N_ * Dout_;  // 1,048,576 f
    float* v0   = s2   + (size_t)B_ * C_ * N_ * Dout_;  // 32,768 f
    float* vsum = v0   + (size_t)B_ * N_ * Dout_;       // 32,768 f

    caps_v0    <<<256,  256, 0, stream>>>(x, W, bias, v0);
    caps_route <<<1024, 256, 0, stream>>>(x, W, v0, s1);
    caps_reduce<<<256,  256, 0, stream>>>(s1, bias, v0, vsum);    // vsum = v0 + v1
    caps_route <<<1024, 256, 0, stream>>>(x, W, vsum, s2);
    caps_reduce<<<256,  256, 0, stream>>>(s2, bias, nullptr, out);
}